// Round 1
// baseline (202.754 us; speedup 1.0000x reference)
//
#include <hip/hip_runtime.h>
#include <hip/hip_bf16.h>

typedef __attribute__((ext_vector_type(4))) float floatx4;
typedef __attribute__((ext_vector_type(8))) short shortx8;

// db4 analysis filters, TRUE-convolution orientation:
// y[m] = sum_i F[i] * xp[2m + 7 - i]  (xp reflect-padded, pl = 6 at every level)
__device__ __constant__ float DLO[8] = {
    -0.010597401784997278f, 0.032883011666982945f,
     0.030841381835986965f, -0.18703481171888114f,
    -0.02798376941698385f,  0.6308807679295904f,
     0.7148465705525415f,   0.23037781330885523f};
__device__ __constant__ float DHI[8] = {
    -0.23037781330885523f,  0.7148465705525415f,
    -0.6308807679295904f,  -0.02798376941698385f,
     0.18703481171888114f,  0.030841381835986965f,
     0.032883011666982945f, -0.010597401784997278f};

__device__ __forceinline__ unsigned short f2bf_rne(float f) {
  unsigned u = __builtin_bit_cast(unsigned, f);
  unsigned r = (u + 0x7FFFu + ((u >> 16) & 1u)) >> 16;
  return (unsigned short)r;
}

// One analysis filter-bank level. pl (left reflect pad) == 6 for n in {64,35,21}.
template <int N, int OUT>
__device__ __forceinline__ void afb(const float* x, float* lo, float* hi) {
#pragma unroll
  for (int m = 0; m < OUT; ++m) {
    float aL = 0.f, aH = 0.f;
#pragma unroll
    for (int i = 0; i < 8; ++i) {
      int s = 2 * m + 1 - i;              // 2m + 7 - i - 6
      s = (s < 0) ? -s : s;               // reflect (no edge repeat)
      s = (s >= N) ? (2 * N - 2 - s) : s;
      float v = x[s];
      aL = fmaf(DLO[i], v, aL);
      aH = fmaf(DHI[i], v, aH);
    }
    lo[m] = aL; hi[m] = aH;
  }
}

// Thread i computes DWT(e_i) = column i of M.  M layout: [84][64] fp32.
__global__ void build_M_kernel(float* __restrict__ M) {
  const int i = threadIdx.x;  // 0..63
  float sig[64];
#pragma unroll
  for (int t = 0; t < 64; ++t) sig[t] = (t == i) ? 1.f : 0.f;
  float lo1[35], hi1[35], lo2[21], hi2[21], lo3[14], hi3[14];
  afb<64, 35>(sig, lo1, hi1);
  afb<35, 21>(lo1, lo2, hi2);
  afb<21, 14>(lo2, lo3, hi3);
#pragma unroll
  for (int t = 0; t < 14; ++t) M[t * 64 + i] = lo3[t];
#pragma unroll
  for (int t = 0; t < 35; ++t) M[(14 + t) * 64 + i] = hi1[t];
#pragma unroll
  for (int t = 0; t < 21; ++t) M[(49 + t) * 64 + i] = hi2[t];
#pragma unroll
  for (int t = 0; t < 14; ++t) M[(70 + t) * 64 + i] = hi3[t];
}

// W2[k][tp*64+hw] = sum_t M[t][tp] * conv_w[k][t][hw], rounded to bf16.
// grid (64, 4): blockIdx.x = k, blockIdx.y = 16-wide tp slice.
__global__ __launch_bounds__(256) void build_w2_kernel(
    const float* __restrict__ M, const float* __restrict__ cw,
    unsigned short* __restrict__ W2) {
  __shared__ float Ml[84 * 64];
  __shared__ float Cl[84 * 64];
  const int k = blockIdx.x;
  const float* cwk = cw + (size_t)k * (84 * 64);
  for (int idx = threadIdx.x; idx < 84 * 64; idx += 256) {
    Ml[idx] = M[idx];
    Cl[idx] = cwk[idx];
  }
  __syncthreads();
  const int tp  = blockIdx.y * 16 + (threadIdx.x >> 4);
  const int hw0 = (threadIdx.x & 15) * 4;
  float a0 = 0.f, a1 = 0.f, a2 = 0.f, a3 = 0.f;
#pragma unroll 4
  for (int t = 0; t < 84; ++t) {
    const float mv = Ml[t * 64 + tp];
    const float4 cv = *(const float4*)&Cl[t * 64 + hw0];
    a0 = fmaf(mv, cv.x, a0);
    a1 = fmaf(mv, cv.y, a1);
    a2 = fmaf(mv, cv.z, a2);
    a3 = fmaf(mv, cv.w, a3);
  }
  uint2 pk;
  pk.x = (unsigned)f2bf_rne(a0) | ((unsigned)f2bf_rne(a1) << 16);
  pk.y = (unsigned)f2bf_rne(a2) | ((unsigned)f2bf_rne(a3) << 16);
  *(uint2*)(W2 + (size_t)k * 4096 + tp * 64 + hw0) = pk;
}

// Streaming GEMM: out[8192][64] = leaky(A[8192][4096] * W2[64][4096]^T + b)
#define BM 32
#define BN 64
#define BK 128
#define LDK 136   // +8 bf16 pad: frag-read row stride 272B -> 2-way bank alias (free)
#define NITER 32  // 4096 / BK

__global__ __launch_bounds__(512) void gemm_kernel(
    const float* __restrict__ A, const unsigned short* __restrict__ W2,
    const float* __restrict__ bias, float* __restrict__ out) {
  __shared__ alignas(16) short As[2][BM * LDK];
  __shared__ alignas(16) short Bs[2][BN * LDK];

  const int tid = threadIdx.x;
  const int b0 = blockIdx.x * BM;

  // staging maps
  const int ar = tid >> 4;             // 0..31  (A row in tile)
  const int ac = (tid & 15) * 8;       // 0..120 (A col in chunk, 8 floats)
  const int bn = tid >> 3;             // 0..63  (W2 row)
  const int bc = (tid & 7) * 16;       // 0..112 (16 bf16)

  const float* aptr = A + (size_t)(b0 + ar) * 4096 + ac;
  const unsigned short* bptr = W2 + (size_t)bn * 4096 + bc;

  // mfma tile assignment: 8 waves -> 2 mtiles x 4 ntiles of 16x16
  const int lane = tid & 63;
  const int wave = tid >> 6;
  const int mt = wave >> 2;
  const int nt = wave & 3;
  const int frow = lane & 15;
  const int fk = (lane >> 4) * 8;

  floatx4 acc = {0.f, 0.f, 0.f, 0.f};

  // depth-2 register prefetch (chunks 0 and 1)
  float4 a0_0 = *(const float4*)(aptr + 0);
  float4 a1_0 = *(const float4*)(aptr + 4);
  uint4  b0_0 = *(const uint4*)(bptr + 0);
  uint4  b1_0 = *(const uint4*)(bptr + 8);
  float4 a0_1 = *(const float4*)(aptr + BK);
  float4 a1_1 = *(const float4*)(aptr + BK + 4);
  uint4  b0_1 = *(const uint4*)(bptr + BK);
  uint4  b1_1 = *(const uint4*)(bptr + BK + 8);

  // Raw barrier: lgkmcnt(0) orders LDS writes, but vmcnt is NOT drained, so
  // the depth-2 global prefetches stay in flight across the barrier (the
  // m97 vmcnt(0)-at-__syncthreads stall would cap HBM utilization here).
#define GSTEP(S, I)                                                          \
  do {                                                                       \
    shortx8 av;                                                              \
    av[0] = (short)f2bf_rne(a0_##S.x); av[1] = (short)f2bf_rne(a0_##S.y);    \
    av[2] = (short)f2bf_rne(a0_##S.z); av[3] = (short)f2bf_rne(a0_##S.w);    \
    av[4] = (short)f2bf_rne(a1_##S.x); av[5] = (short)f2bf_rne(a1_##S.y);    \
    av[6] = (short)f2bf_rne(a1_##S.z); av[7] = (short)f2bf_rne(a1_##S.w);    \
    *(shortx8*)&As[S][ar * LDK + ac] = av;                                   \
    *(uint4*)&Bs[S][bn * LDK + bc] = b0_##S;                                 \
    *(uint4*)&Bs[S][bn * LDK + bc + 8] = b1_##S;                             \
    __asm__ __volatile__("s_waitcnt lgkmcnt(0)\n\ts_barrier" ::: "memory");  \
    if ((I) + 2 < NITER) {                                                   \
      const int c2 = ((I) + 2) * BK;                                         \
      a0_##S = *(const float4*)(aptr + c2);                                  \
      a1_##S = *(const float4*)(aptr + c2 + 4);                              \
      b0_##S = *(const uint4*)(bptr + c2);                                   \
      b1_##S = *(const uint4*)(bptr + c2 + 8);                               \
    }                                                                        \
    _Pragma("unroll")                                                        \
    for (int kk = 0; kk < 4; ++kk) {                                         \
      shortx8 af = *(const shortx8*)&As[S][(mt * 16 + frow) * LDK + kk * 32 + fk]; \
      shortx8 bf = *(const shortx8*)&Bs[S][(nt * 16 + frow) * LDK + kk * 32 + fk]; \
      acc = __builtin_amdgcn_mfma_f32_16x16x32_bf16(af, bf, acc, 0, 0, 0);   \
    }                                                                        \
  } while (0)

  for (int i = 0; i < NITER; i += 2) {
    GSTEP(0, i);
    GSTEP(1, i + 1);
  }
#undef GSTEP

  // epilogue: D layout col = lane&15 (n), row = (lane>>4)*4 + r (m)
  const int ocol = nt * 16 + (lane & 15);
  const int orow0 = b0 + mt * 16 + (lane >> 4) * 4;
  const float bv = bias[ocol];
#pragma unroll
  for (int r = 0; r < 4; ++r) {
    float v = acc[r] + bv;
    out[(size_t)(orow0 + r) * 64 + ocol] = (v >= 0.f) ? v : 1.0e-3f * v;
  }
}

extern "C" void kernel_launch(void* const* d_in, const int* in_sizes, int n_in,
                              void* d_out, int out_size, void* d_ws, size_t ws_size,
                              hipStream_t stream) {
  const float* x      = (const float*)d_in[0];  // [8192,1,64,8,8]
  const float* conv_w = (const float*)d_in[1];  // [64,84,8,8]
  const float* conv_b = (const float*)d_in[2];  // [64]
  float* out = (float*)d_out;                   // [8192,64]

  float* Mws = (float*)d_ws;                                   // 84*64 fp32 = 21504 B
  unsigned short* W2 = (unsigned short*)((char*)d_ws + 32768); // 64*4096 bf16 = 512 KB

  build_M_kernel<<<1, 64, 0, stream>>>(Mws);
  build_w2_kernel<<<dim3(64, 4), 256, 0, stream>>>(Mws, conv_w, W2);
  gemm_kernel<<<256, 512, 0, stream>>>(x, W2, conv_b, out);
}